// Round 12
// baseline (113.366 us; speedup 1.0000x reference)
//
#include <hip/hip_runtime.h>
#include <hip/hip_bf16.h>

#define N_NODES 50000
#define N_EDGES 500000
#define IN_FEATS 96
#define OUT_FEATS 128
#define N_ETYPES 4
#define KCAT (N_ETYPES * IN_FEATS)  // 384

typedef __attribute__((ext_vector_type(8))) short short8;
typedef __attribute__((ext_vector_type(4))) float f32x4;

static __device__ inline short f2bf_bits(float f) {
    __hip_bfloat16 h = __float2bfloat16(f);
    return *reinterpret_cast<short*>(&h);
}
static __device__ inline unsigned pack2bf(float lo, float hi) {
    unsigned l = (unsigned short)f2bf_bits(lo);
    unsigned h = (unsigned short)f2bf_bits(hi);
    return l | (h << 16);
}

// ---------------------------------------------------------------------------
// k_init: zero deg[] AND pre-convert W (f32 [4][128][128], first 96 cols) to
// bf16 Wb [4*128][96] (stored as u32 pairs).
// ---------------------------------------------------------------------------
__global__ __launch_bounds__(256) void k_init(int* __restrict__ deg,
                                              const float* __restrict__ W,
                                              unsigned* __restrict__ Wb_u32) {
    int g = blockIdx.x * 256 + threadIdx.x;
    if (g < N_NODES) deg[g] = 0;
    if (g < 512 * 48) {
        int row = g / 48, pair = g % 48;
        float lo = W[(size_t)row * OUT_FEATS + pair * 2];
        float hi = W[(size_t)row * OUT_FEATS + pair * 2 + 1];
        Wb_u32[g] = pack2bf(lo, hi);
    }
}

// ---------------------------------------------------------------------------
// k_hist: degree histogram + per-edge rank (rank store is NT: read-once later)
// ---------------------------------------------------------------------------
__global__ __launch_bounds__(256) void k_hist(const int* __restrict__ dst,
                                              int* __restrict__ deg,
                                              int* __restrict__ rank) {
    int e = blockIdx.x * 256 + threadIdx.x;
    if (e < N_EDGES) {
        int r = atomicAdd(&deg[dst[e]], 1);
        __builtin_nontemporal_store(r, &rank[e]);
    }
}

__global__ __launch_bounds__(256) void k_scan1(const int* __restrict__ in, int n,
                                               int* __restrict__ out, int* __restrict__ bsum) {
    int g = blockIdx.x * 256 + threadIdx.x;
    int lane = threadIdx.x & 63, wave = threadIdx.x >> 6;
    int v = (g < n) ? in[g] : 0;
    int orig = v;
    for (int off = 1; off < 64; off <<= 1) {
        int u = __shfl_up(v, off);
        if (lane >= off) v += u;
    }
    __shared__ int wsum[4];
    if (lane == 63) wsum[wave] = v;
    __syncthreads();
    if (threadIdx.x == 0) {
        int s = 0;
        for (int w = 0; w < 4; ++w) { int t = wsum[w]; wsum[w] = s; s += t; }
        bsum[blockIdx.x] = s;
    }
    __syncthreads();
    int excl = v - orig + wsum[wave];
    if (g < n) out[g] = excl;
}

// k_scan3: each block computes its own prefix over bsum (196 ints) then adds.
__global__ __launch_bounds__(256) void k_scan3(int* __restrict__ pos, const int* __restrict__ bsum, int n) {
    const int b = blockIdx.x;
    const int t = threadIdx.x;
    const int lane = t & 63, wave = t >> 6;
    __shared__ int ws[4];
    int v = (t < b) ? bsum[t] : 0;   // b <= 195 < 256
#pragma unroll
    for (int off = 32; off > 0; off >>= 1) v += __shfl_down(v, off);
    if (lane == 0) ws[wave] = v;
    __syncthreads();
    if (t == 0) ws[0] = ws[0] + ws[1] + ws[2] + ws[3];
    __syncthreads();
    int prefix = ws[0];
    int g = b * 256 + t;
    if (g < n) pos[g] += prefix;
}

// k_bin: atomic-free scatter using precomputed rank (packed store NT)
__global__ __launch_bounds__(256) void k_bin(const int* __restrict__ dst, const int* __restrict__ src,
                                             const int* __restrict__ etypes,
                                             const int* __restrict__ pos, const int* __restrict__ rank,
                                             int* __restrict__ packed) {
    int e = blockIdx.x * 256 + threadIdx.x;
    if (e < N_EDGES) {
        int slot = pos[dst[e]] + rank[e];
        __builtin_nontemporal_store(src[e] | (etypes[e] << 16), &packed[slot]);
    }
}

// ---------------------------------------------------------------------------
// Per-node aggregation (r5-proven form): 1 wave per node, float2 lanes,
// 4-deep unrolled gathers for ILP. packed loads NT (read-once), Scat stores
// NT (written-once; keep L2/L3 for the reused feat working set).
// ---------------------------------------------------------------------------
__global__ __launch_bounds__(64) void k_agg(const float2* __restrict__ feat2,
                                            const int* __restrict__ pos, const int* __restrict__ deg,
                                            const int* __restrict__ packed,
                                            unsigned* __restrict__ Scat_u32,
                                            float* __restrict__ counts) {
    const int d = blockIdx.x;
    const int lane = threadIdx.x;
    const bool act = lane < 48;
    const int start = pos[d], cnt = deg[d];

    float2 a0 = {0.f, 0.f}, a1 = {0.f, 0.f}, a2 = {0.f, 0.f}, a3 = {0.f, 0.f};
    int c0 = 0, c1 = 0, c2 = 0, c3 = 0;
    const float2 zero = {0.f, 0.f};

    int i = 0;
    for (; i + 4 <= cnt; i += 4) {
        int p0 = __builtin_nontemporal_load(&packed[start + i + 0]);
        int p1 = __builtin_nontemporal_load(&packed[start + i + 1]);
        int p2 = __builtin_nontemporal_load(&packed[start + i + 2]);
        int p3 = __builtin_nontemporal_load(&packed[start + i + 3]);
        float2 v0 = act ? feat2[(size_t)(p0 & 0xFFFF) * 48 + lane] : zero;
        float2 v1 = act ? feat2[(size_t)(p1 & 0xFFFF) * 48 + lane] : zero;
        float2 v2 = act ? feat2[(size_t)(p2 & 0xFFFF) * 48 + lane] : zero;
        float2 v3 = act ? feat2[(size_t)(p3 & 0xFFFF) * 48 + lane] : zero;
        int e0 = p0 >> 16, e1 = p1 >> 16, e2 = p2 >> 16, e3 = p3 >> 16;
        if (e0 == 0) { a0.x += v0.x; a0.y += v0.y; ++c0; }
        else if (e0 == 1) { a1.x += v0.x; a1.y += v0.y; ++c1; }
        else if (e0 == 2) { a2.x += v0.x; a2.y += v0.y; ++c2; }
        else              { a3.x += v0.x; a3.y += v0.y; ++c3; }
        if (e1 == 0) { a0.x += v1.x; a0.y += v1.y; ++c0; }
        else if (e1 == 1) { a1.x += v1.x; a1.y += v1.y; ++c1; }
        else if (e1 == 2) { a2.x += v1.x; a2.y += v1.y; ++c2; }
        else              { a3.x += v1.x; a3.y += v1.y; ++c3; }
        if (e2 == 0) { a0.x += v2.x; a0.y += v2.y; ++c0; }
        else if (e2 == 1) { a1.x += v2.x; a1.y += v2.y; ++c1; }
        else if (e2 == 2) { a2.x += v2.x; a2.y += v2.y; ++c2; }
        else              { a3.x += v2.x; a3.y += v2.y; ++c3; }
        if (e3 == 0) { a0.x += v3.x; a0.y += v3.y; ++c0; }
        else if (e3 == 1) { a1.x += v3.x; a1.y += v3.y; ++c1; }
        else if (e3 == 2) { a2.x += v3.x; a2.y += v3.y; ++c2; }
        else              { a3.x += v3.x; a3.y += v3.y; ++c3; }
    }
    for (; i < cnt; ++i) {
        int p = __builtin_nontemporal_load(&packed[start + i]);
        float2 v = act ? feat2[(size_t)(p & 0xFFFF) * 48 + lane] : zero;
        int e = p >> 16;
        if (e == 0) { a0.x += v.x; a0.y += v.y; ++c0; }
        else if (e == 1) { a1.x += v.x; a1.y += v.y; ++c1; }
        else if (e == 2) { a2.x += v.x; a2.y += v.y; ++c2; }
        else              { a3.x += v.x; a3.y += v.y; ++c3; }
    }

    if (act) {
        size_t base = (size_t)d * (KCAT / 2) + lane;  // u32 row stride 192
        __builtin_nontemporal_store(pack2bf(a0.x, a0.y), &Scat_u32[base]);
        __builtin_nontemporal_store(pack2bf(a1.x, a1.y), &Scat_u32[base + 48]);
        __builtin_nontemporal_store(pack2bf(a2.x, a2.y), &Scat_u32[base + 96]);
        __builtin_nontemporal_store(pack2bf(a3.x, a3.y), &Scat_u32[base + 144]);
    }
    if (lane < 4) counts[d * 4 + lane] = (float)(lane == 0 ? c0 : lane == 1 ? c1 : lane == 2 ? c2 : c3);
}

// ---------------------------------------------------------------------------
// MFMA GEMM (r11 form): 64x128 tile, 4 waves over N. Scat loads NT
// (read-once), out stores NT (write-once). Wb/b/counts stay cached.
// ---------------------------------------------------------------------------
#define LDT 104  // padded LDS row (bf16 elems)

__global__ __launch_bounds__(256) void k_gemm(const __hip_bfloat16* __restrict__ Scat,
                                              const short* __restrict__ Wb,
                                              const float* __restrict__ b,
                                              const float* __restrict__ counts,
                                              float* __restrict__ out) {
    __shared__ __align__(16) __hip_bfloat16 As[64][LDT];
    __shared__ __align__(16) __hip_bfloat16 Bs[128][LDT];
    const int m0 = blockIdx.x * 64;
    const int tid = threadIdx.x, lane = tid & 63, wave = tid >> 6;
    const int wn = wave;  // N split: wave covers cols [wn*32, wn*32+32)

    f32x4 acc[4][2];
#pragma unroll
    for (int i = 0; i < 4; ++i)
#pragma unroll
        for (int jj = 0; jj < 2; ++jj) acc[i][jj] = (f32x4){0.f, 0.f, 0.f, 0.f};

    for (int ks = 0; ks < 4; ++ks) {  // ks == etype
#pragma unroll
        for (int it = 0; it < 3; ++it) {
            int idx = tid + it * 256;          // 0..767
            int row = idx / 12, c8 = idx % 12;
            int gm = m0 + row;
            if (gm > N_NODES - 1) gm = N_NODES - 1;
            short8 v = __builtin_nontemporal_load(
                reinterpret_cast<const short8*>(&Scat[(size_t)gm * KCAT + ks * IN_FEATS + c8 * 8]));
            *reinterpret_cast<short8*>(&As[row][c8 * 8]) = v;
        }
#pragma unroll
        for (int it = 0; it < 6; ++it) {
            int idx = tid + it * 256;          // 0..1535
            int row = idx / 12, c8 = idx % 12;
            short8 v = *reinterpret_cast<const short8*>(&Wb[((size_t)ks * OUT_FEATS + row) * IN_FEATS + c8 * 8]);
            *reinterpret_cast<short8*>(&Bs[row][c8 * 8]) = v;
        }
        __syncthreads();
#pragma unroll
        for (int kk = 0; kk < 3; ++kk) {
            short8 af[4], bf[2];
#pragma unroll
            for (int mi = 0; mi < 4; ++mi)
                af[mi] = *reinterpret_cast<const short8*>(&As[mi * 16 + (lane & 15)][kk * 32 + (lane >> 4) * 8]);
#pragma unroll
            for (int ni = 0; ni < 2; ++ni)
                bf[ni] = *reinterpret_cast<const short8*>(&Bs[wn * 32 + ni * 16 + (lane & 15)][kk * 32 + (lane >> 4) * 8]);
#pragma unroll
            for (int mi = 0; mi < 4; ++mi)
#pragma unroll
                for (int ni = 0; ni < 2; ++ni)
                    acc[mi][ni] = __builtin_amdgcn_mfma_f32_16x16x32_bf16(af[mi], bf[ni], acc[mi][ni], 0, 0, 0);
        }
        __syncthreads();
    }

#pragma unroll
    for (int mi = 0; mi < 4; ++mi) {
#pragma unroll
        for (int r = 0; r < 4; ++r) {
            int m = m0 + mi * 16 + (lane >> 4) * 4 + r;
            if (m < N_NODES) {
                float4 c4 = *reinterpret_cast<const float4*>(&counts[m * 4]);
#pragma unroll
                for (int ni = 0; ni < 2; ++ni) {
                    int n = wn * 32 + ni * 16 + (lane & 15);
                    float bias = c4.x * b[n] + c4.y * b[OUT_FEATS + n] +
                                 c4.z * b[2 * OUT_FEATS + n] + c4.w * b[3 * OUT_FEATS + n];
                    __builtin_nontemporal_store(acc[mi][ni][r] + bias, &out[(size_t)m * OUT_FEATS + n]);
                }
            }
        }
    }
}

// ---------------------------------------------------------------------------
// Fallback (ws too small): direct per-(edge, j) dot product with atomics.
// ---------------------------------------------------------------------------
__global__ __launch_bounds__(256) void edge_direct(const float* __restrict__ feat,
                                                   const int* __restrict__ etypes,
                                                   const int* __restrict__ src,
                                                   const int* __restrict__ dst,
                                                   const float* __restrict__ W,
                                                   const float* __restrict__ b,
                                                   float* __restrict__ out) {
    int gid = blockIdx.x * 256 + threadIdx.x;
    int e = gid >> 7;
    int j = gid & 127;
    if (e >= N_EDGES) return;
    int et = etypes[e];
    int s = src[e];
    int d = dst[e];
    const float* f = feat + (size_t)s * IN_FEATS;
    const float* w = W + ((size_t)et * OUT_FEATS + j) * OUT_FEATS;
    float acc = b[et * OUT_FEATS + j];
    for (int k = 0; k < IN_FEATS; ++k) acc += f[k] * w[k];
    atomicAdd(&out[(size_t)d * OUT_FEATS + j], acc);
}

extern "C" void kernel_launch(void* const* d_in, const int* in_sizes, int n_in,
                              void* d_out, int out_size, void* d_ws, size_t ws_size,
                              hipStream_t stream) {
    const float* feat  = (const float*)d_in[0];
    const int*   etyps = (const int*)d_in[1];
    const int*   src   = (const int*)d_in[2];
    const int*   dst   = (const int*)d_in[3];
    const float* W     = (const float*)d_in[4];
    const float* b     = (const float*)d_in[5];
    float* out = (float*)d_out;

    const size_t off_scat   = 0;                                        // 38,400,000
    const size_t off_counts = off_scat + (size_t)N_NODES * KCAT * 2;    // +800,000
    const size_t off_deg    = off_counts + (size_t)N_NODES * 4 * 4;     // +200,000
    const size_t off_pos    = off_deg + (size_t)N_NODES * 4;            // +200,000
    const size_t off_rank   = off_pos + (size_t)N_NODES * 4;            // +2,000,000
    const size_t off_packed = off_rank + (size_t)N_EDGES * 4;           // +2,000,000
    const size_t off_bsum   = off_packed + (size_t)N_EDGES * 4;
    const size_t off_wb     = off_bsum + 1024;                          // +98,304
    const size_t need = off_wb + (size_t)512 * IN_FEATS * 2;

    if (ws_size >= need) {
        char* ws = (char*)d_ws;
        __hip_bfloat16* Scat = (__hip_bfloat16*)(ws + off_scat);
        unsigned* Scat_u32 = (unsigned*)(ws + off_scat);
        float* counts = (float*)(ws + off_counts);
        int* deg    = (int*)(ws + off_deg);
        int* pos    = (int*)(ws + off_pos);
        int* rank   = (int*)(ws + off_rank);
        int* packed = (int*)(ws + off_packed);
        int* bsum   = (int*)(ws + off_bsum);
        unsigned* Wb_u32 = (unsigned*)(ws + off_wb);
        short* Wb = (short*)(ws + off_wb);

        const int nScanBlocks = (N_NODES + 255) / 256;  // 196
        const int nEdgeBlocks = (N_EDGES + 255) / 256;  // 1954

        k_init<<<nScanBlocks, 256, 0, stream>>>(deg, W, Wb_u32);
        k_hist<<<nEdgeBlocks, 256, 0, stream>>>(dst, deg, rank);
        k_scan1<<<nScanBlocks, 256, 0, stream>>>(deg, N_NODES, pos, bsum);
        k_scan3<<<nScanBlocks, 256, 0, stream>>>(pos, bsum, N_NODES);
        k_bin<<<nEdgeBlocks, 256, 0, stream>>>(dst, src, etyps, pos, rank, packed);
        k_agg<<<N_NODES, 64, 0, stream>>>((const float2*)feat, pos, deg, packed, Scat_u32, counts);
        k_gemm<<<(N_NODES + 63) / 64, 256, 0, stream>>>(Scat, Wb, b, counts, out);
    } else {
        hipMemsetAsync(d_out, 0, (size_t)out_size * sizeof(float), stream);
        int nthreads = N_EDGES * OUT_FEATS;
        edge_direct<<<nthreads / 256, 256, 0, stream>>>(feat, etyps, src, dst, W, b, out);
    }
}

// Round 13
// 99.060 us; speedup vs baseline: 1.1444x; 1.1444x over previous
//
#include <hip/hip_runtime.h>
#include <hip/hip_bf16.h>

#define N_NODES 50000
#define N_EDGES 500000
#define IN_FEATS 96
#define OUT_FEATS 128
#define N_ETYPES 4
#define KCAT (N_ETYPES * IN_FEATS)  // 384

typedef __attribute__((ext_vector_type(8))) short short8;
typedef __attribute__((ext_vector_type(4))) float f32x4;

static __device__ inline short f2bf_bits(float f) {
    __hip_bfloat16 h = __float2bfloat16(f);
    return *reinterpret_cast<short*>(&h);
}
static __device__ inline unsigned pack2bf(float lo, float hi) {
    unsigned l = (unsigned short)f2bf_bits(lo);
    unsigned h = (unsigned short)f2bf_bits(hi);
    return l | (h << 16);
}

// ---------------------------------------------------------------------------
// k_init: zero deg[] AND pre-convert W (f32 [4][128][128], first 96 cols) to
// bf16 Wb [4*128][96] (stored as u32 pairs).
// ---------------------------------------------------------------------------
__global__ __launch_bounds__(256) void k_init(int* __restrict__ deg,
                                              const float* __restrict__ W,
                                              unsigned* __restrict__ Wb_u32) {
    int g = blockIdx.x * 256 + threadIdx.x;
    if (g < N_NODES) deg[g] = 0;
    if (g < 512 * 48) {
        int row = g / 48, pair = g % 48;
        float lo = W[(size_t)row * OUT_FEATS + pair * 2];
        float hi = W[(size_t)row * OUT_FEATS + pair * 2 + 1];
        Wb_u32[g] = pack2bf(lo, hi);
    }
}

// ---------------------------------------------------------------------------
// k_hist: degree histogram + per-edge rank
// ---------------------------------------------------------------------------
__global__ __launch_bounds__(256) void k_hist(const int* __restrict__ dst,
                                              int* __restrict__ deg,
                                              int* __restrict__ rank) {
    int e = blockIdx.x * 256 + threadIdx.x;
    if (e < N_EDGES) rank[e] = atomicAdd(&deg[dst[e]], 1);
}

__global__ __launch_bounds__(256) void k_scan1(const int* __restrict__ in, int n,
                                               int* __restrict__ out, int* __restrict__ bsum) {
    int g = blockIdx.x * 256 + threadIdx.x;
    int lane = threadIdx.x & 63, wave = threadIdx.x >> 6;
    int v = (g < n) ? in[g] : 0;
    int orig = v;
    for (int off = 1; off < 64; off <<= 1) {
        int u = __shfl_up(v, off);
        if (lane >= off) v += u;
    }
    __shared__ int wsum[4];
    if (lane == 63) wsum[wave] = v;
    __syncthreads();
    if (threadIdx.x == 0) {
        int s = 0;
        for (int w = 0; w < 4; ++w) { int t = wsum[w]; wsum[w] = s; s += t; }
        bsum[blockIdx.x] = s;
    }
    __syncthreads();
    int excl = v - orig + wsum[wave];
    if (g < n) out[g] = excl;
}

// k_scan3: each block computes its own prefix over bsum (196 ints) then adds.
__global__ __launch_bounds__(256) void k_scan3(int* __restrict__ pos, const int* __restrict__ bsum, int n) {
    const int b = blockIdx.x;
    const int t = threadIdx.x;
    const int lane = t & 63, wave = t >> 6;
    __shared__ int ws[4];
    int v = (t < b) ? bsum[t] : 0;   // b <= 195 < 256
#pragma unroll
    for (int off = 32; off > 0; off >>= 1) v += __shfl_down(v, off);
    if (lane == 0) ws[wave] = v;
    __syncthreads();
    if (t == 0) ws[0] = ws[0] + ws[1] + ws[2] + ws[3];
    __syncthreads();
    int prefix = ws[0];
    int g = b * 256 + t;
    if (g < n) pos[g] += prefix;
}

// k_bin: atomic-free scatter using precomputed rank
__global__ __launch_bounds__(256) void k_bin(const int* __restrict__ dst, const int* __restrict__ src,
                                             const int* __restrict__ etypes,
                                             const int* __restrict__ pos, const int* __restrict__ rank,
                                             int* __restrict__ packed) {
    int e = blockIdx.x * 256 + threadIdx.x;
    if (e < N_EDGES) {
        int slot = pos[dst[e]] + rank[e];
        packed[slot] = src[e] | (etypes[e] << 16);  // src < 65536, et < 4
    }
}

// ---------------------------------------------------------------------------
// Per-node aggregation (r5-proven form): 1 wave per node, float2 lanes,
// 4-deep unrolled gathers for ILP. Scat[d][et*96+k] bf16; counts f32.
// ---------------------------------------------------------------------------
__global__ __launch_bounds__(64) void k_agg(const float2* __restrict__ feat2,
                                            const int* __restrict__ pos, const int* __restrict__ deg,
                                            const int* __restrict__ packed,
                                            unsigned* __restrict__ Scat_u32,
                                            float* __restrict__ counts) {
    const int d = blockIdx.x;
    const int lane = threadIdx.x;
    const bool act = lane < 48;
    const int start = pos[d], cnt = deg[d];

    float2 a0 = {0.f, 0.f}, a1 = {0.f, 0.f}, a2 = {0.f, 0.f}, a3 = {0.f, 0.f};
    int c0 = 0, c1 = 0, c2 = 0, c3 = 0;
    const float2 zero = {0.f, 0.f};

    int i = 0;
    for (; i + 4 <= cnt; i += 4) {
        int p0 = packed[start + i + 0];
        int p1 = packed[start + i + 1];
        int p2 = packed[start + i + 2];
        int p3 = packed[start + i + 3];
        float2 v0 = act ? feat2[(size_t)(p0 & 0xFFFF) * 48 + lane] : zero;
        float2 v1 = act ? feat2[(size_t)(p1 & 0xFFFF) * 48 + lane] : zero;
        float2 v2 = act ? feat2[(size_t)(p2 & 0xFFFF) * 48 + lane] : zero;
        float2 v3 = act ? feat2[(size_t)(p3 & 0xFFFF) * 48 + lane] : zero;
        int e0 = p0 >> 16, e1 = p1 >> 16, e2 = p2 >> 16, e3 = p3 >> 16;
        if (e0 == 0) { a0.x += v0.x; a0.y += v0.y; ++c0; }
        else if (e0 == 1) { a1.x += v0.x; a1.y += v0.y; ++c1; }
        else if (e0 == 2) { a2.x += v0.x; a2.y += v0.y; ++c2; }
        else              { a3.x += v0.x; a3.y += v0.y; ++c3; }
        if (e1 == 0) { a0.x += v1.x; a0.y += v1.y; ++c0; }
        else if (e1 == 1) { a1.x += v1.x; a1.y += v1.y; ++c1; }
        else if (e1 == 2) { a2.x += v1.x; a2.y += v1.y; ++c2; }
        else              { a3.x += v1.x; a3.y += v1.y; ++c3; }
        if (e2 == 0) { a0.x += v2.x; a0.y += v2.y; ++c0; }
        else if (e2 == 1) { a1.x += v2.x; a1.y += v2.y; ++c1; }
        else if (e2 == 2) { a2.x += v2.x; a2.y += v2.y; ++c2; }
        else              { a3.x += v2.x; a3.y += v2.y; ++c3; }
        if (e3 == 0) { a0.x += v3.x; a0.y += v3.y; ++c0; }
        else if (e3 == 1) { a1.x += v3.x; a1.y += v3.y; ++c1; }
        else if (e3 == 2) { a2.x += v3.x; a2.y += v3.y; ++c2; }
        else              { a3.x += v3.x; a3.y += v3.y; ++c3; }
    }
    for (; i < cnt; ++i) {
        int p = packed[start + i];
        float2 v = act ? feat2[(size_t)(p & 0xFFFF) * 48 + lane] : zero;
        int e = p >> 16;
        if (e == 0) { a0.x += v.x; a0.y += v.y; ++c0; }
        else if (e == 1) { a1.x += v.x; a1.y += v.y; ++c1; }
        else if (e == 2) { a2.x += v.x; a2.y += v.y; ++c2; }
        else              { a3.x += v.x; a3.y += v.y; ++c3; }
    }

    if (act) {
        size_t base = (size_t)d * (KCAT / 2) + lane;  // u32 row stride 192
        Scat_u32[base]       = pack2bf(a0.x, a0.y);
        Scat_u32[base + 48]  = pack2bf(a1.x, a1.y);
        Scat_u32[base + 96]  = pack2bf(a2.x, a2.y);
        Scat_u32[base + 144] = pack2bf(a3.x, a3.y);
    }
    if (lane < 4) counts[d * 4 + lane] = (float)(lane == 0 ? c0 : lane == 1 ? c1 : lane == 2 ? c2 : c3);
}

// ---------------------------------------------------------------------------
// MFMA GEMM: 64x128 tile per block (782 blocks -> ~3 blocks/CU). 4 waves
// split N into 4x32. LDT=104 keeps frag reads ~conflict-free.
// ---------------------------------------------------------------------------
#define LDT 104  // padded LDS row (bf16 elems)

__global__ __launch_bounds__(256) void k_gemm(const __hip_bfloat16* __restrict__ Scat,
                                              const short* __restrict__ Wb,
                                              const float* __restrict__ b,
                                              const float* __restrict__ counts,
                                              float* __restrict__ out) {
    __shared__ __align__(16) __hip_bfloat16 As[64][LDT];
    __shared__ __align__(16) __hip_bfloat16 Bs[128][LDT];
    const int m0 = blockIdx.x * 64;
    const int tid = threadIdx.x, lane = tid & 63, wave = tid >> 6;
    const int wn = wave;  // N split: wave covers cols [wn*32, wn*32+32)

    f32x4 acc[4][2];
#pragma unroll
    for (int i = 0; i < 4; ++i)
#pragma unroll
        for (int jj = 0; jj < 2; ++jj) acc[i][jj] = (f32x4){0.f, 0.f, 0.f, 0.f};

    for (int ks = 0; ks < 4; ++ks) {  // ks == etype
#pragma unroll
        for (int it = 0; it < 3; ++it) {
            int idx = tid + it * 256;          // 0..767
            int row = idx / 12, c8 = idx % 12;
            int gm = m0 + row;
            if (gm > N_NODES - 1) gm = N_NODES - 1;
            short8 v = *reinterpret_cast<const short8*>(&Scat[(size_t)gm * KCAT + ks * IN_FEATS + c8 * 8]);
            *reinterpret_cast<short8*>(&As[row][c8 * 8]) = v;
        }
#pragma unroll
        for (int it = 0; it < 6; ++it) {
            int idx = tid + it * 256;          // 0..1535
            int row = idx / 12, c8 = idx % 12;
            short8 v = *reinterpret_cast<const short8*>(&Wb[((size_t)ks * OUT_FEATS + row) * IN_FEATS + c8 * 8]);
            *reinterpret_cast<short8*>(&Bs[row][c8 * 8]) = v;
        }
        __syncthreads();
#pragma unroll
        for (int kk = 0; kk < 3; ++kk) {
            short8 af[4], bf[2];
#pragma unroll
            for (int mi = 0; mi < 4; ++mi)
                af[mi] = *reinterpret_cast<const short8*>(&As[mi * 16 + (lane & 15)][kk * 32 + (lane >> 4) * 8]);
#pragma unroll
            for (int ni = 0; ni < 2; ++ni)
                bf[ni] = *reinterpret_cast<const short8*>(&Bs[wn * 32 + ni * 16 + (lane & 15)][kk * 32 + (lane >> 4) * 8]);
#pragma unroll
            for (int mi = 0; mi < 4; ++mi)
#pragma unroll
                for (int ni = 0; ni < 2; ++ni)
                    acc[mi][ni] = __builtin_amdgcn_mfma_f32_16x16x32_bf16(af[mi], bf[ni], acc[mi][ni], 0, 0, 0);
        }
        __syncthreads();
    }

#pragma unroll
    for (int mi = 0; mi < 4; ++mi) {
#pragma unroll
        for (int r = 0; r < 4; ++r) {
            int m = m0 + mi * 16 + (lane >> 4) * 4 + r;
            if (m < N_NODES) {
                float4 c4 = *reinterpret_cast<const float4*>(&counts[m * 4]);
#pragma unroll
                for (int ni = 0; ni < 2; ++ni) {
                    int n = wn * 32 + ni * 16 + (lane & 15);
                    float bias = c4.x * b[n] + c4.y * b[OUT_FEATS + n] +
                                 c4.z * b[2 * OUT_FEATS + n] + c4.w * b[3 * OUT_FEATS + n];
                    out[(size_t)m * OUT_FEATS + n] = acc[mi][ni][r] + bias;
                }
            }
        }
    }
}

// ---------------------------------------------------------------------------
// Fallback (ws too small): direct per-(edge, j) dot product with atomics.
// ---------------------------------------------------------------------------
__global__ __launch_bounds__(256) void edge_direct(const float* __restrict__ feat,
                                                   const int* __restrict__ etypes,
                                                   const int* __restrict__ src,
                                                   const int* __restrict__ dst,
                                                   const float* __restrict__ W,
                                                   const float* __restrict__ b,
                                                   float* __restrict__ out) {
    int gid = blockIdx.x * 256 + threadIdx.x;
    int e = gid >> 7;
    int j = gid & 127;
    if (e >= N_EDGES) return;
    int et = etypes[e];
    int s = src[e];
    int d = dst[e];
    const float* f = feat + (size_t)s * IN_FEATS;
    const float* w = W + ((size_t)et * OUT_FEATS + j) * OUT_FEATS;
    float acc = b[et * OUT_FEATS + j];
    for (int k = 0; k < IN_FEATS; ++k) acc += f[k] * w[k];
    atomicAdd(&out[(size_t)d * OUT_FEATS + j], acc);
}

extern "C" void kernel_launch(void* const* d_in, const int* in_sizes, int n_in,
                              void* d_out, int out_size, void* d_ws, size_t ws_size,
                              hipStream_t stream) {
    const float* feat  = (const float*)d_in[0];
    const int*   etyps = (const int*)d_in[1];
    const int*   src   = (const int*)d_in[2];
    const int*   dst   = (const int*)d_in[3];
    const float* W     = (const float*)d_in[4];
    const float* b     = (const float*)d_in[5];
    float* out = (float*)d_out;

    const size_t off_scat   = 0;                                        // 38,400,000
    const size_t off_counts = off_scat + (size_t)N_NODES * KCAT * 2;    // +800,000
    const size_t off_deg    = off_counts + (size_t)N_NODES * 4 * 4;     // +200,000
    const size_t off_pos    = off_deg + (size_t)N_NODES * 4;            // +200,000
    const size_t off_rank   = off_pos + (size_t)N_NODES * 4;            // +2,000,000
    const size_t off_packed = off_rank + (size_t)N_EDGES * 4;           // +2,000,000
    const size_t off_bsum   = off_packed + (size_t)N_EDGES * 4;
    const size_t off_wb     = off_bsum + 1024;                          // +98,304
    const size_t need = off_wb + (size_t)512 * IN_FEATS * 2;

    if (ws_size >= need) {
        char* ws = (char*)d_ws;
        __hip_bfloat16* Scat = (__hip_bfloat16*)(ws + off_scat);
        unsigned* Scat_u32 = (unsigned*)(ws + off_scat);
        float* counts = (float*)(ws + off_counts);
        int* deg    = (int*)(ws + off_deg);
        int* pos    = (int*)(ws + off_pos);
        int* rank   = (int*)(ws + off_rank);
        int* packed = (int*)(ws + off_packed);
        int* bsum   = (int*)(ws + off_bsum);
        unsigned* Wb_u32 = (unsigned*)(ws + off_wb);
        short* Wb = (short*)(ws + off_wb);

        const int nScanBlocks = (N_NODES + 255) / 256;  // 196
        const int nEdgeBlocks = (N_EDGES + 255) / 256;  // 1954

        k_init<<<nScanBlocks, 256, 0, stream>>>(deg, W, Wb_u32);
        k_hist<<<nEdgeBlocks, 256, 0, stream>>>(dst, deg, rank);
        k_scan1<<<nScanBlocks, 256, 0, stream>>>(deg, N_NODES, pos, bsum);
        k_scan3<<<nScanBlocks, 256, 0, stream>>>(pos, bsum, N_NODES);
        k_bin<<<nEdgeBlocks, 256, 0, stream>>>(dst, src, etyps, pos, rank, packed);
        k_agg<<<N_NODES, 64, 0, stream>>>((const float2*)feat, pos, deg, packed, Scat_u32, counts);
        k_gemm<<<(N_NODES + 63) / 64, 256, 0, stream>>>(Scat, Wb, b, counts, out);
    } else {
        hipMemsetAsync(d_out, 0, (size_t)out_size * sizeof(float), stream);
        int nthreads = N_EDGES * OUT_FEATS;
        edge_direct<<<nthreads / 256, 256, 0, stream>>>(feat, etyps, src, dst, W, b, out);
    }
}